// Round 4
// baseline (633.523 us; speedup 1.0000x reference)
//
#include <hip/hip_runtime.h>
#include <hip/hip_bf16.h>

// ---------------------------------------------------------------------------
// Fully-fused SwinV2 window attention, one workgroup per window.
//   B=4096 windows, N=64 tokens, DIM=256, H=8 heads, HD=32, NW=1024 masks.
// Round 4: 3 barriers (was 7). x+c staged up-front in two swizzled 32KB LDS
// buffers; Q/K/V GEMMs back-to-back; V->PV A-frag transpose is free in regs
// (same-lane identity); q/k lane-transpose transits through the dead c buffer;
// mask+bias read straight from L2 in softmax. LDS = 64KB, 2 blocks/CU.
// ---------------------------------------------------------------------------

typedef __attribute__((ext_vector_type(4))) float f32x4;
typedef __attribute__((ext_vector_type(8))) short bf16x8;   // 8 bf16 in 4 VGPRs
typedef __attribute__((ext_vector_type(4))) unsigned int u32x4;
typedef __attribute__((ext_vector_type(2))) unsigned int u32x2;
typedef __attribute__((ext_vector_type(4))) unsigned short u16x4;

#define MFMA16(a, b, c) __builtin_amdgcn_mfma_f32_16x16x32_bf16((a), (b), (c), 0, 0, 0)

union FragAB {
  bf16x8 v;
  ushort u[8];
  u32x4  q4;
  u32x2  q2[2];
};

__device__ __forceinline__ ushort f2b(float f) {
  union { __hip_bfloat16 h; ushort u; } cv;
  cv.h = __float2bfloat16(f);          // native gfx950 cvt, RNE
  return cv.u;
}

__device__ __forceinline__ bf16x8 ldfrag(const ushort* p) {   // 16B-aligned
  FragAB f;
  f.q4 = *(const u32x4*)p;
  return f.v;
}

__device__ __forceinline__ f32x4 fzero() {
  f32x4 z = {0.0f, 0.0f, 0.0f, 0.0f};
  return z;
}

// ---------------------------------------------------------------------------
// Prep: bf16-convert + MFMA-fragment-repack weights; bias2[h][n][m]; scales.
// Packed weight index: o*256 + kg*32 + lg*8 + e  <->  k = 4lg+e | 16+4lg+(e-4)
// ---------------------------------------------------------------------------
__global__ void prep_kernel(const float* __restrict__ qw, const float* __restrict__ kvw,
                            const float* __restrict__ pw, const float* __restrict__ rpb,
                            const float* __restrict__ lsc,
                            ushort* __restrict__ qwb, ushort* __restrict__ kvwb,
                            ushort* __restrict__ pwb, float* __restrict__ bias2,
                            float* __restrict__ scale) {
  int t = blockIdx.x * blockDim.x + threadIdx.x;
  int stride = gridDim.x * blockDim.x;
  for (int i = t; i < 256 * 256; i += stride) {
    int o = i >> 8, rem = i & 255;
    int kg = rem >> 5, r2 = rem & 31, lg = r2 >> 3, e = r2 & 7;
    int k = (kg << 5) + (lg << 2) + (e < 4 ? e : e + 12);
    qwb[i] = f2b(qw[(o << 8) + k]);
    pwb[i] = f2b(pw[(o << 8) + k]);
  }
  for (int i = t; i < 512 * 256; i += stride) {
    int o = i >> 8, rem = i & 255;
    int kg = rem >> 5, r2 = rem & 31, lg = r2 >> 3, e = r2 & 7;
    int k = (kg << 5) + (lg << 2) + (e < 4 ? e : e + 12);
    kvwb[i] = f2b(kvw[(o << 8) + k]);
  }
  // bias2[h][n][m] = rpb_table[RPI[n][m]][h]   (n = query, m = key; m fastest)
  for (int i = t; i < 8 * 64 * 64; i += stride) {
    int h = i >> 12, n = (i >> 6) & 63, m = i & 63;
    int idx = ((n >> 3) - (m >> 3) + 7) * 15 + ((n & 7) - (m & 7) + 7);
    bias2[i] = rpb[idx * 8 + h];
  }
  if (t < 8) scale[t] = __expf(fminf(lsc[t], 4.6051701859880914f));  // log(100)
}

// ---------------------------------------------------------------------------
// Main fused kernel: 512 threads = 8 waves; wave w owns head w / col block w.
// LDS tiles xs/cs: byte = row*512 + (2*packedcol ^ ((row&7)<<4)) -> b128 reads
// are bank-uniform. Transit slab: 64B rows, XOR (row&7)<<3.
// ---------------------------------------------------------------------------
__global__ __launch_bounds__(512, 4)
void wattn_fused(const float* __restrict__ xg, const float* __restrict__ cg,
                 const float* __restrict__ maskg,
                 const float* __restrict__ qb, const float* __restrict__ kvb,
                 const float* __restrict__ pb,
                 const ushort* __restrict__ qwb, const ushort* __restrict__ kvwb,
                 const ushort* __restrict__ pwb,
                 const float* __restrict__ bias2, const float* __restrict__ scaleg,
                 float* __restrict__ outg) {
  __shared__ __align__(16) ushort xs[64 * 256];   // x -> att (swizzled)
  __shared__ __align__(16) ushort cs[64 * 256];   // c -> q/k transit slabs

  const int b    = blockIdx.x;
  const int wid  = b & 1023;          // window id (b = batch*1024 + w)
  const int tid  = threadIdx.x;
  const int w    = tid >> 6;          // wave / head 0..7
  const int lane = tid & 63;
  const int lg   = lane >> 4;         // 0..3
  const int lc   = lane & 15;         // 0..15
  const int c0   = w << 5;            // this wave's 32-col block base
  const int sw4  = (lc & 7) << 4;     // tile-read swizzle
  const int sw3  = (lc & 7) << 3;     // transit-read swizzle

  char* xsb = (char*)xs;
  char* csb = (char*)cs;

  // ---- Phase A: stage x -> xs, c -> cs (bf16, packed+swizzled) ----
  {
    const float4* srcx = (const float4*)(xg + (size_t)b * 16384);
    const float4* srcc = (const float4*)(cg + (size_t)b * 16384);
    float4 rx[8], rc[8];
#pragma unroll
    for (int it = 0; it < 8; ++it) rx[it] = srcx[tid + it * 512];
#pragma unroll
    for (int it = 0; it < 8; ++it) rc[it] = srcc[tid + it * 512];
#pragma unroll
    for (int it = 0; it < 8; ++it) {
      int i = tid + it * 512;
      int row = i >> 6;
      int colf = (i & 63) << 2;
      int pcb = 2 * ((colf & ~31) + (((colf & 15) >> 2) << 3) + ((colf & 16) ? 4 : 0));
      int off = row * 512 + (pcb ^ ((row & 7) << 4));
      u16x4 p0, p1;
      p0[0] = f2b(rx[it].x); p0[1] = f2b(rx[it].y); p0[2] = f2b(rx[it].z); p0[3] = f2b(rx[it].w);
      p1[0] = f2b(rc[it].x); p1[1] = f2b(rc[it].y); p1[2] = f2b(rc[it].z); p1[3] = f2b(rc[it].w);
      *(u16x4*)(xsb + off) = p0;
      *(u16x4*)(csb + off) = p1;
    }
  }
  __syncthreads();   // ---- bar1 ----

  const int cp0 = ((lc >> 2) << 3) + (lc & 3);   // packed col of chan lc (ch 16+lc -> +4)

  // ---- Q GEMM (xs) -> L2-norm -> qpk (packed bf16 pairs, regs) ----
  unsigned int qpk[16], kpk[16];
  {
    f32x4 acc[4][2];
#pragma unroll
    for (int mt = 0; mt < 4; ++mt)
#pragma unroll
      for (int nt = 0; nt < 2; ++nt) acc[mt][nt] = fzero();
#pragma unroll
    for (int kg = 0; kg < 8; ++kg) {
      bf16x8 a[4], bb[2];
#pragma unroll
      for (int mt = 0; mt < 4; ++mt) {
        int row = mt * 16 + lc;
        a[mt] = ldfrag((const ushort*)(xsb + row * 512 + (((kg << 6) + (lg << 4)) ^ sw4)));
      }
#pragma unroll
      for (int nt = 0; nt < 2; ++nt)
        bb[nt] = ldfrag(qwb + ((c0 + nt * 16 + lc) << 8) + (kg << 5) + (lg << 3));
#pragma unroll
      for (int mt = 0; mt < 4; ++mt)
#pragma unroll
        for (int nt = 0; nt < 2; ++nt)
          acc[mt][nt] = MFMA16(a[mt], bb[nt], acc[mt][nt]);
    }
    float bias0 = qb[c0 + lc], bias1 = qb[c0 + 16 + lc];
#pragma unroll
    for (int mt = 0; mt < 4; ++mt) {
#pragma unroll
      for (int reg = 0; reg < 4; ++reg) {
        float v0 = acc[mt][0][reg] + bias0;
        float v1 = acc[mt][1][reg] + bias1;
        float ss = v0 * v0 + v1 * v1;
        ss += __shfl_xor(ss, 1);
        ss += __shfl_xor(ss, 2);
        ss += __shfl_xor(ss, 4);
        ss += __shfl_xor(ss, 8);
        float inv = 1.0f / fmaxf(sqrtf(ss), 1e-12f);
        qpk[mt * 4 + reg] = (unsigned int)f2b(v0 * inv) | ((unsigned int)f2b(v1 * inv) << 16);
      }
    }
  }

  // ---- K GEMM (cs) -> L2-norm -> kpk ----
  {
    f32x4 acc[4][2];
#pragma unroll
    for (int mt = 0; mt < 4; ++mt)
#pragma unroll
      for (int nt = 0; nt < 2; ++nt) acc[mt][nt] = fzero();
#pragma unroll
    for (int kg = 0; kg < 8; ++kg) {
      bf16x8 a[4], bb[2];
#pragma unroll
      for (int mt = 0; mt < 4; ++mt) {
        int row = mt * 16 + lc;
        a[mt] = ldfrag((const ushort*)(csb + row * 512 + (((kg << 6) + (lg << 4)) ^ sw4)));
      }
#pragma unroll
      for (int nt = 0; nt < 2; ++nt)
        bb[nt] = ldfrag(kvwb + ((c0 + nt * 16 + lc) << 8) + (kg << 5) + (lg << 3));
#pragma unroll
      for (int mt = 0; mt < 4; ++mt)
#pragma unroll
        for (int nt = 0; nt < 2; ++nt)
          acc[mt][nt] = MFMA16(a[mt], bb[nt], acc[mt][nt]);
    }
    float bias0 = kvb[c0 + lc], bias1 = kvb[c0 + 16 + lc];
#pragma unroll
    for (int mt = 0; mt < 4; ++mt) {
#pragma unroll
      for (int reg = 0; reg < 4; ++reg) {
        float v0 = acc[mt][0][reg] + bias0;
        float v1 = acc[mt][1][reg] + bias1;
        float ss = v0 * v0 + v1 * v1;
        ss += __shfl_xor(ss, 1);
        ss += __shfl_xor(ss, 2);
        ss += __shfl_xor(ss, 4);
        ss += __shfl_xor(ss, 8);
        float inv = 1.0f / fmaxf(sqrtf(ss), 1e-12f);
        kpk[mt * 4 + reg] = (unsigned int)f2b(v0 * inv) | ((unsigned int)f2b(v1 * inv) << 16);
      }
    }
  }

  // ---- V GEMM (cs) -> PV A-frags DIRECTLY in regs (same-lane identity) ----
  FragAB av[2][2];   // av[dmt][kt]
  {
    f32x4 acc[4][2];
#pragma unroll
    for (int mt = 0; mt < 4; ++mt)
#pragma unroll
      for (int nt = 0; nt < 2; ++nt) acc[mt][nt] = fzero();
#pragma unroll
    for (int kg = 0; kg < 8; ++kg) {
      bf16x8 a[4], bb[2];
#pragma unroll
      for (int mt = 0; mt < 4; ++mt) {
        int row = mt * 16 + lc;
        a[mt] = ldfrag((const ushort*)(csb + row * 512 + (((kg << 6) + (lg << 4)) ^ sw4)));
      }
#pragma unroll
      for (int nt = 0; nt < 2; ++nt)
        bb[nt] = ldfrag(kvwb + ((256 + c0 + nt * 16 + lc) << 8) + (kg << 5) + (lg << 3));
#pragma unroll
      for (int mt = 0; mt < 4; ++mt)
#pragma unroll
        for (int nt = 0; nt < 2; ++nt)
          acc[mt][nt] = MFMA16(a[mt], bb[nt], acc[mt][nt]);
    }
    float bias0 = kvb[256 + c0 + lc], bias1 = kvb[256 + c0 + 16 + lc];
#pragma unroll
    for (int kt = 0; kt < 2; ++kt)
#pragma unroll
      for (int j = 0; j < 4; ++j) {
        av[0][kt].u[j]     = f2b(acc[2 * kt][0][j] + bias0);
        av[0][kt].u[4 + j] = f2b(acc[2 * kt + 1][0][j] + bias0);
        av[1][kt].u[j]     = f2b(acc[2 * kt][1][j] + bias1);
        av[1][kt].u[4 + j] = f2b(acc[2 * kt + 1][1][j] + bias1);
      }
  }
  __syncthreads();   // ---- bar2: all cs reads done; xs(x) reads done ----

  // ---- q/k lane-transpose through per-wave slab in dead cs ----
  bf16x8 qf[4], kf[4];
  {
    char* slab = csb + (w << 12);   // 4096 B per wave, rows of 64 B
#pragma unroll
    for (int mt = 0; mt < 4; ++mt)
#pragma unroll
      for (int reg = 0; reg < 4; ++reg) {
        int row = mt * 16 + (lg << 2) + reg;
        int off = row * 64 + ((2 * cp0) ^ ((row & 7) << 3));
        unsigned int v = qpk[mt * 4 + reg];
        *(ushort*)(slab + off)       = (ushort)(v & 0xffff);
        *(ushort*)(slab + (off ^ 8)) = (ushort)(v >> 16);
      }
#pragma unroll
    for (int t4 = 0; t4 < 4; ++t4) {
      int row = (t4 << 4) + lc;
      int off = row * 64 + ((lg << 4) ^ sw3);
      FragAB f;
      f.q2[0] = *(const u32x2*)(slab + off);
      f.q2[1] = *(const u32x2*)(slab + (off ^ 8));
      qf[t4] = f.v;
    }
#pragma unroll
    for (int mt = 0; mt < 4; ++mt)
#pragma unroll
      for (int reg = 0; reg < 4; ++reg) {
        int row = mt * 16 + (lg << 2) + reg;
        int off = row * 64 + ((2 * cp0) ^ ((row & 7) << 3));
        unsigned int v = kpk[mt * 4 + reg];
        *(ushort*)(slab + off)       = (ushort)(v & 0xffff);
        *(ushort*)(slab + (off ^ 8)) = (ushort)(v >> 16);
      }
#pragma unroll
    for (int t4 = 0; t4 < 4; ++t4) {
      int row = (t4 << 4) + lc;
      int off = row * 64 + ((lg << 4) ^ sw3);
      FragAB f;
      f.q2[0] = *(const u32x2*)(slab + off);
      f.q2[1] = *(const u32x2*)(slab + (off ^ 8));
      kf[t4] = f.v;
    }
  }

  // ---- Attention: per-nt QK^T -> softmax (mask/bias from L2) -> PV ----
  f32x4 ot[2][4];
#pragma unroll
  for (int dmt = 0; dmt < 2; ++dmt)
#pragma unroll
    for (int nt = 0; nt < 4; ++nt) ot[dmt][nt] = fzero();
  {
    const float sc = scaleg[w];
    const float* b2 = bias2 + (w << 12);
    const float* mq = maskg + (size_t)wid * 4096;
#pragma unroll
    for (int nt = 0; nt < 4; ++nt) {
      f32x4 st[4];
#pragma unroll
      for (int mt = 0; mt < 4; ++mt)
        st[mt] = MFMA16(kf[mt], qf[nt], fzero());
      const int n = nt * 16 + lc;
      float mx = -3.0e38f;
#pragma unroll
      for (int mt = 0; mt < 4; ++mt) {
        f32x4 bv = *(const f32x4*)(b2 + (n << 6) + (mt << 4) + (lg << 2));
        f32x4 mk = *(const f32x4*)(mq + (n << 6) + (mt << 4) + (lg << 2));
#pragma unroll
        for (int reg = 0; reg < 4; ++reg) {
          float val = st[mt][reg] * sc + bv[reg] + mk[reg];
          st[mt][reg] = val;
          mx = fmaxf(mx, val);
        }
      }
      mx = fmaxf(mx, __shfl_xor(mx, 16));
      mx = fmaxf(mx, __shfl_xor(mx, 32));
      float sm = 0.0f;
#pragma unroll
      for (int mt = 0; mt < 4; ++mt)
#pragma unroll
        for (int reg = 0; reg < 4; ++reg) {
          float e = __expf(st[mt][reg] - mx);
          st[mt][reg] = e;
          sm += e;
        }
      sm += __shfl_xor(sm, 16);
      sm += __shfl_xor(sm, 32);
      float inv = 1.0f / sm;
#pragma unroll
      for (int kt = 0; kt < 2; ++kt) {
        FragAB pfr;
#pragma unroll
        for (int j = 0; j < 4; ++j) {
          pfr.u[j]     = f2b(st[2 * kt][j] * inv);
          pfr.u[4 + j] = f2b(st[2 * kt + 1][j] * inv);
        }
#pragma unroll
        for (int dmt = 0; dmt < 2; ++dmt)
          ot[dmt][nt] = MFMA16(av[dmt][kt].v, pfr.v, ot[dmt][nt]);
      }
    }
  }

  // ---- att-write into xs (x is dead since bar2): one b128 per nt ----
#pragma unroll
  for (int nt = 0; nt < 4; ++nt) {
    int row = nt * 16 + lc;
    FragAB o8;
#pragma unroll
    for (int j = 0; j < 4; ++j) {
      o8.u[j]     = f2b(ot[0][nt][j]);
      o8.u[4 + j] = f2b(ot[1][nt][j]);
    }
    *(u32x4*)(xsb + row * 512 + (((w << 6) + (lg << 4)) ^ sw4)) = o8.q4;
  }
  __syncthreads();   // ---- bar3: att complete ----

  // ---- Proj GEMM: out = att @ pw^T + pb  (f32 store) ----
  {
    f32x4 acc[4][2];
#pragma unroll
    for (int mt = 0; mt < 4; ++mt)
#pragma unroll
      for (int nt = 0; nt < 2; ++nt) acc[mt][nt] = fzero();
#pragma unroll
    for (int kg = 0; kg < 8; ++kg) {
      bf16x8 a[4], bb[2];
#pragma unroll
      for (int mt = 0; mt < 4; ++mt) {
        int row = mt * 16 + lc;
        a[mt] = ldfrag((const ushort*)(xsb + row * 512 + (((kg << 6) + (lg << 4)) ^ sw4)));
      }
#pragma unroll
      for (int nt = 0; nt < 2; ++nt)
        bb[nt] = ldfrag(pwb + ((c0 + nt * 16 + lc) << 8) + (kg << 5) + (lg << 3));
#pragma unroll
      for (int mt = 0; mt < 4; ++mt)
#pragma unroll
        for (int nt = 0; nt < 2; ++nt)
          acc[mt][nt] = MFMA16(a[mt], bb[nt], acc[mt][nt]);
    }
    float bias0 = pb[c0 + lc], bias1 = pb[c0 + 16 + lc];
    float* op = outg + (size_t)b * 16384;
#pragma unroll
    for (int mt = 0; mt < 4; ++mt) {
#pragma unroll
      for (int reg = 0; reg < 4; ++reg) {
        int row = mt * 16 + (lg << 2) + reg;
        op[(row << 8) + c0 + lc]      = acc[mt][0][reg] + bias0;
        op[(row << 8) + c0 + 16 + lc] = acc[mt][1][reg] + bias1;
      }
    }
  }
}

// ---------------------------------------------------------------------------
extern "C" void kernel_launch(void* const* d_in, const int* in_sizes, int n_in,
                              void* d_out, int out_size, void* d_ws, size_t ws_size,
                              hipStream_t stream) {
  const float* x    = (const float*)d_in[0];
  const float* c    = (const float*)d_in[1];
  const float* mask = (const float*)d_in[2];
  const float* q_w  = (const float*)d_in[3];
  const float* q_b  = (const float*)d_in[4];
  const float* kv_w = (const float*)d_in[5];
  const float* kv_b = (const float*)d_in[6];
  const float* lsc  = (const float*)d_in[7];
  const float* rpb  = (const float*)d_in[8];
  const float* p_w  = (const float*)d_in[9];
  const float* p_b  = (const float*)d_in[10];

  char* ws = (char*)d_ws;
  ushort* qwb   = (ushort*)(ws);                       // 131072 B
  ushort* kvwb  = (ushort*)(ws + 131072);              // 262144 B
  ushort* pwb   = (ushort*)(ws + 131072 + 262144);     // 131072 B
  float*  bias2 = (float*)(ws + 524288);               // 131072 B
  float*  scale = (float*)(ws + 524288 + 131072);      // 32 B

  prep_kernel<<<64, 256, 0, stream>>>(q_w, kv_w, p_w, rpb, lsc, qwb, kvwb, pwb, bias2, scale);
  wattn_fused<<<4096, 512, 0, stream>>>(x, c, mask, q_b, kv_b, p_b, qwb, kvwb, pwb,
                                        bias2, scale, (float*)d_out);
}

// Round 5
// 590.008 us; speedup vs baseline: 1.0738x; 1.0738x over previous
//
#include <hip/hip_runtime.h>
#include <hip/hip_bf16.h>

// ---------------------------------------------------------------------------
// Fully-fused SwinV2 window attention, one workgroup per window.
//   B=4096 windows, N=64 tokens, DIM=256, H=8 heads, HD=32, NW=1024 masks.
// Round 5: ZERO LDS transit. Q,K projections computed TRANSPOSED by swapping
// MFMA operands (D = mfma(W,X) -> D[chan][token]); QK^T A/B fragments and PV
// A-fragments then fall out of the projection accumulators by SAME-LANE
// identities (no shuffles, no LDS). 3 barriers, LDS = 64KB (xs + cs only),
// 2 blocks/CU, mask/bias read from L2 in softmax.
// ---------------------------------------------------------------------------

typedef __attribute__((ext_vector_type(4))) float f32x4;
typedef __attribute__((ext_vector_type(8))) short bf16x8;   // 8 bf16 in 4 VGPRs
typedef __attribute__((ext_vector_type(4))) unsigned int u32x4;
typedef __attribute__((ext_vector_type(2))) unsigned int u32x2;
typedef __attribute__((ext_vector_type(4))) unsigned short u16x4;

#define MFMA16(a, b, c) __builtin_amdgcn_mfma_f32_16x16x32_bf16((a), (b), (c), 0, 0, 0)

union FragAB {
  bf16x8 v;
  ushort u[8];
  u32x4  q4;
  u32x2  q2[2];
};

__device__ __forceinline__ ushort f2b(float f) {
  union { __hip_bfloat16 h; ushort u; } cv;
  cv.h = __float2bfloat16(f);          // native gfx950 cvt, RNE
  return cv.u;
}

__device__ __forceinline__ bf16x8 ldfrag(const ushort* p) {   // 16B-aligned
  FragAB f;
  f.q4 = *(const u32x4*)p;
  return f.v;
}

__device__ __forceinline__ f32x4 fzero() {
  f32x4 z = {0.0f, 0.0f, 0.0f, 0.0f};
  return z;
}

// ---------------------------------------------------------------------------
// Prep: bf16-convert + MFMA-fragment-repack weights; bias2[h][n][m]; scales.
// Packed weight index: o*256 + kg*32 + lg*8 + e  <->  k = 4lg+e | 16+4lg+(e-4)
// ---------------------------------------------------------------------------
__global__ void prep_kernel(const float* __restrict__ qw, const float* __restrict__ kvw,
                            const float* __restrict__ pw, const float* __restrict__ rpb,
                            const float* __restrict__ lsc,
                            ushort* __restrict__ qwb, ushort* __restrict__ kvwb,
                            ushort* __restrict__ pwb, float* __restrict__ bias2,
                            float* __restrict__ scale) {
  int t = blockIdx.x * blockDim.x + threadIdx.x;
  int stride = gridDim.x * blockDim.x;
  for (int i = t; i < 256 * 256; i += stride) {
    int o = i >> 8, rem = i & 255;
    int kg = rem >> 5, r2 = rem & 31, lg = r2 >> 3, e = r2 & 7;
    int k = (kg << 5) + (lg << 2) + (e < 4 ? e : e + 12);
    qwb[i] = f2b(qw[(o << 8) + k]);
    pwb[i] = f2b(pw[(o << 8) + k]);
  }
  for (int i = t; i < 512 * 256; i += stride) {
    int o = i >> 8, rem = i & 255;
    int kg = rem >> 5, r2 = rem & 31, lg = r2 >> 3, e = r2 & 7;
    int k = (kg << 5) + (lg << 2) + (e < 4 ? e : e + 12);
    kvwb[i] = f2b(kvw[(o << 8) + k]);
  }
  // bias2[h][n][m] = rpb_table[RPI[n][m]][h]   (n = query, m = key; m fastest)
  for (int i = t; i < 8 * 64 * 64; i += stride) {
    int h = i >> 12, n = (i >> 6) & 63, m = i & 63;
    int idx = ((n >> 3) - (m >> 3) + 7) * 15 + ((n & 7) - (m & 7) + 7);
    bias2[i] = rpb[idx * 8 + h];
  }
  if (t < 8) scale[t] = __expf(fminf(lsc[t], 4.6051701859880914f));  // log(100)
}

// ---------------------------------------------------------------------------
// Main fused kernel: 512 threads = 8 waves; wave w owns head w / col block w.
// LDS tiles xs/cs: byte = row*512 + (2*packedcol ^ ((row&7)<<4)) -> b128 reads
// are <=2-way bank aliased (free).
// ---------------------------------------------------------------------------
__global__ __launch_bounds__(512, 4)
void wattn_fused(const float* __restrict__ xg, const float* __restrict__ cg,
                 const float* __restrict__ maskg,
                 const float* __restrict__ qb, const float* __restrict__ kvb,
                 const float* __restrict__ pb,
                 const ushort* __restrict__ qwb, const ushort* __restrict__ kvwb,
                 const ushort* __restrict__ pwb,
                 const float* __restrict__ bias2, const float* __restrict__ scaleg,
                 float* __restrict__ outg) {
  __shared__ __align__(16) ushort xs[64 * 256];   // x -> att (swizzled)
  __shared__ __align__(16) ushort cs[64 * 256];   // c (swizzled)

  const int b    = blockIdx.x;
  const int wid  = b & 1023;          // window id (b = batch*1024 + w)
  const int tid  = threadIdx.x;
  const int w    = tid >> 6;          // wave / head 0..7
  const int lane = tid & 63;
  const int lg   = lane >> 4;         // 0..3
  const int lc   = lane & 15;         // 0..15
  const int c0   = w << 5;            // this wave's 32-col block base
  const int sw4  = (lc & 7) << 4;     // tile-read swizzle

  char* xsb = (char*)xs;
  char* csb = (char*)cs;

  // ---- Phase A: stage x -> xs, c -> cs (bf16, packed+swizzled) ----
  {
    const float4* srcx = (const float4*)(xg + (size_t)b * 16384);
    const float4* srcc = (const float4*)(cg + (size_t)b * 16384);
    float4 rx[8], rc[8];
#pragma unroll
    for (int it = 0; it < 8; ++it) rx[it] = srcx[tid + it * 512];
#pragma unroll
    for (int it = 0; it < 8; ++it) rc[it] = srcc[tid + it * 512];
#pragma unroll
    for (int it = 0; it < 8; ++it) {
      int i = tid + it * 512;
      int row = i >> 6;
      int colf = (i & 63) << 2;
      int pcb = 2 * ((colf & ~31) + (((colf & 15) >> 2) << 3) + ((colf & 16) ? 4 : 0));
      int off = row * 512 + (pcb ^ ((row & 7) << 4));
      u16x4 p0, p1;
      p0[0] = f2b(rx[it].x); p0[1] = f2b(rx[it].y); p0[2] = f2b(rx[it].z); p0[3] = f2b(rx[it].w);
      p1[0] = f2b(rc[it].x); p1[1] = f2b(rc[it].y); p1[2] = f2b(rc[it].z); p1[3] = f2b(rc[it].w);
      *(u16x4*)(xsb + off) = p0;
      *(u16x4*)(csb + off) = p1;
    }
  }
  __syncthreads();   // ---- bar1 ----

  // ---- Q^T GEMM: D[chan][token] = mfma(Wq, X) -> norm -> qf (same-lane) ----
  bf16x8 qf[4], kf[4];
  {
    f32x4 acc[2][4];   // acc[chan-tile mo][token-tile nt]
#pragma unroll
    for (int mo = 0; mo < 2; ++mo)
#pragma unroll
      for (int nt = 0; nt < 4; ++nt) acc[mo][nt] = fzero();
#pragma unroll
    for (int kg = 0; kg < 8; ++kg) {
      bf16x8 a[4], bb[2];
#pragma unroll
      for (int nt = 0; nt < 4; ++nt) {
        int row = nt * 16 + lc;
        a[nt] = ldfrag((const ushort*)(xsb + row * 512 + (((kg << 6) + (lg << 4)) ^ sw4)));
      }
#pragma unroll
      for (int mo = 0; mo < 2; ++mo)
        bb[mo] = ldfrag(qwb + ((c0 + mo * 16 + lc) << 8) + (kg << 5) + (lg << 3));
#pragma unroll
      for (int mo = 0; mo < 2; ++mo)
#pragma unroll
        for (int nt = 0; nt < 4; ++nt)
          acc[mo][nt] = MFMA16(bb[mo], a[nt], acc[mo][nt]);   // SWAPPED -> transposed
    }
    // bias: chan = c0 + 16*mo + 4*lg + reg  (uniform across lc)
    float bq[2][4];
#pragma unroll
    for (int mo = 0; mo < 2; ++mo)
#pragma unroll
      for (int reg = 0; reg < 4; ++reg) bq[mo][reg] = qb[c0 + mo * 16 + (lg << 2) + reg];
#pragma unroll
    for (int nt = 0; nt < 4; ++nt) {
      float ss = 0.0f;
#pragma unroll
      for (int mo = 0; mo < 2; ++mo)
#pragma unroll
        for (int reg = 0; reg < 4; ++reg) {
          float v = acc[mo][nt][reg] + bq[mo][reg];
          acc[mo][nt][reg] = v;
          ss += v * v;
        }
      ss += __shfl_xor(ss, 16);
      ss += __shfl_xor(ss, 32);
      float inv = 1.0f / fmaxf(sqrtf(ss), 1e-12f);
      FragAB f;
#pragma unroll
      for (int j = 0; j < 4; ++j) {
        f.u[j]     = f2b(acc[0][nt][j] * inv);
        f.u[4 + j] = f2b(acc[1][nt][j] * inv);
      }
      qf[nt] = f.v;
    }
  }

  // ---- K^T GEMM (from cs) -> norm -> kf (same-lane) ----
  {
    f32x4 acc[2][4];
#pragma unroll
    for (int mo = 0; mo < 2; ++mo)
#pragma unroll
      for (int nt = 0; nt < 4; ++nt) acc[mo][nt] = fzero();
#pragma unroll
    for (int kg = 0; kg < 8; ++kg) {
      bf16x8 a[4], bb[2];
#pragma unroll
      for (int nt = 0; nt < 4; ++nt) {
        int row = nt * 16 + lc;
        a[nt] = ldfrag((const ushort*)(csb + row * 512 + (((kg << 6) + (lg << 4)) ^ sw4)));
      }
#pragma unroll
      for (int mo = 0; mo < 2; ++mo)
        bb[mo] = ldfrag(kvwb + ((c0 + mo * 16 + lc) << 8) + (kg << 5) + (lg << 3));
#pragma unroll
      for (int mo = 0; mo < 2; ++mo)
#pragma unroll
        for (int nt = 0; nt < 4; ++nt)
          acc[mo][nt] = MFMA16(bb[mo], a[nt], acc[mo][nt]);   // SWAPPED -> transposed
    }
    float bk[2][4];
#pragma unroll
    for (int mo = 0; mo < 2; ++mo)
#pragma unroll
      for (int reg = 0; reg < 4; ++reg) bk[mo][reg] = kvb[c0 + mo * 16 + (lg << 2) + reg];
#pragma unroll
    for (int nt = 0; nt < 4; ++nt) {
      float ss = 0.0f;
#pragma unroll
      for (int mo = 0; mo < 2; ++mo)
#pragma unroll
        for (int reg = 0; reg < 4; ++reg) {
          float v = acc[mo][nt][reg] + bk[mo][reg];
          acc[mo][nt][reg] = v;
          ss += v * v;
        }
      ss += __shfl_xor(ss, 16);
      ss += __shfl_xor(ss, 32);
      float inv = 1.0f / fmaxf(sqrtf(ss), 1e-12f);
      FragAB f;
#pragma unroll
      for (int j = 0; j < 4; ++j) {
        f.u[j]     = f2b(acc[0][nt][j] * inv);
        f.u[4 + j] = f2b(acc[1][nt][j] * inv);
      }
      kf[nt] = f.v;
    }
  }

  // ---- V GEMM (non-transposed) -> PV A-frags in regs (same-lane) ----
  FragAB av[2][2];   // av[dmt][kt]
  {
    f32x4 acc[4][2];   // acc[token-tile mt][chan-tile dmt]
#pragma unroll
    for (int mt = 0; mt < 4; ++mt)
#pragma unroll
      for (int nt = 0; nt < 2; ++nt) acc[mt][nt] = fzero();
#pragma unroll
    for (int kg = 0; kg < 8; ++kg) {
      bf16x8 a[4], bb[2];
#pragma unroll
      for (int mt = 0; mt < 4; ++mt) {
        int row = mt * 16 + lc;
        a[mt] = ldfrag((const ushort*)(csb + row * 512 + (((kg << 6) + (lg << 4)) ^ sw4)));
      }
#pragma unroll
      for (int nt = 0; nt < 2; ++nt)
        bb[nt] = ldfrag(kvwb + ((256 + c0 + nt * 16 + lc) << 8) + (kg << 5) + (lg << 3));
#pragma unroll
      for (int mt = 0; mt < 4; ++mt)
#pragma unroll
        for (int nt = 0; nt < 2; ++nt)
          acc[mt][nt] = MFMA16(a[mt], bb[nt], acc[mt][nt]);
    }
    float bias0 = kvb[256 + c0 + lc], bias1 = kvb[256 + c0 + 16 + lc];
#pragma unroll
    for (int kt = 0; kt < 2; ++kt)
#pragma unroll
      for (int j = 0; j < 4; ++j) {
        av[0][kt].u[j]     = f2b(acc[2 * kt][0][j] + bias0);
        av[0][kt].u[4 + j] = f2b(acc[2 * kt + 1][0][j] + bias0);
        av[1][kt].u[j]     = f2b(acc[2 * kt][1][j] + bias1);
        av[1][kt].u[4 + j] = f2b(acc[2 * kt + 1][1][j] + bias1);
      }
  }

  // ---- Attention: per-nt QK^T -> softmax (mask/bias from L2) -> PV ----
  f32x4 ot[2][4];
#pragma unroll
  for (int dmt = 0; dmt < 2; ++dmt)
#pragma unroll
    for (int nt = 0; nt < 4; ++nt) ot[dmt][nt] = fzero();
  {
    const float sc = scaleg[w];
    const float* b2 = bias2 + (w << 12);
    const float* mq = maskg + (size_t)wid * 4096;
#pragma unroll
    for (int nt = 0; nt < 4; ++nt) {
      f32x4 st[4];
#pragma unroll
      for (int mt = 0; mt < 4; ++mt)
        st[mt] = MFMA16(kf[mt], qf[nt], fzero());
      const int n = nt * 16 + lc;
      float mx = -3.0e38f;
#pragma unroll
      for (int mt = 0; mt < 4; ++mt) {
        f32x4 bv = *(const f32x4*)(b2 + (n << 6) + (mt << 4) + (lg << 2));
        f32x4 mk = *(const f32x4*)(mq + (n << 6) + (mt << 4) + (lg << 2));
#pragma unroll
        for (int reg = 0; reg < 4; ++reg) {
          float val = st[mt][reg] * sc + bv[reg] + mk[reg];
          st[mt][reg] = val;
          mx = fmaxf(mx, val);
        }
      }
      mx = fmaxf(mx, __shfl_xor(mx, 16));
      mx = fmaxf(mx, __shfl_xor(mx, 32));
      float sm = 0.0f;
#pragma unroll
      for (int mt = 0; mt < 4; ++mt)
#pragma unroll
        for (int reg = 0; reg < 4; ++reg) {
          float e = __expf(st[mt][reg] - mx);
          st[mt][reg] = e;
          sm += e;
        }
      sm += __shfl_xor(sm, 16);
      sm += __shfl_xor(sm, 32);
      float inv = 1.0f / sm;
#pragma unroll
      for (int kt = 0; kt < 2; ++kt) {
        FragAB pfr;
#pragma unroll
        for (int j = 0; j < 4; ++j) {
          pfr.u[j]     = f2b(st[2 * kt][j] * inv);
          pfr.u[4 + j] = f2b(st[2 * kt + 1][j] * inv);
        }
#pragma unroll
        for (int dmt = 0; dmt < 2; ++dmt)
          ot[dmt][nt] = MFMA16(av[dmt][kt].v, pfr.v, ot[dmt][nt]);
      }
    }
  }
  __syncthreads();   // ---- bar2: all xs(x)/cs reads done ----

  // ---- att-write into xs: one b128 per nt ----
#pragma unroll
  for (int nt = 0; nt < 4; ++nt) {
    int row = nt * 16 + lc;
    FragAB o8;
#pragma unroll
    for (int j = 0; j < 4; ++j) {
      o8.u[j]     = f2b(ot[0][nt][j]);
      o8.u[4 + j] = f2b(ot[1][nt][j]);
    }
    *(u32x4*)(xsb + row * 512 + (((w << 6) + (lg << 4)) ^ sw4)) = o8.q4;
  }
  __syncthreads();   // ---- bar3: att complete ----

  // ---- Proj GEMM: out = att @ pw^T + pb  (f32 store) ----
  {
    f32x4 acc[4][2];
#pragma unroll
    for (int mt = 0; mt < 4; ++mt)
#pragma unroll
      for (int nt = 0; nt < 2; ++nt) acc[mt][nt] = fzero();
#pragma unroll
    for (int kg = 0; kg < 8; ++kg) {
      bf16x8 a[4], bb[2];
#pragma unroll
      for (int mt = 0; mt < 4; ++mt) {
        int row = mt * 16 + lc;
        a[mt] = ldfrag((const ushort*)(xsb + row * 512 + (((kg << 6) + (lg << 4)) ^ sw4)));
      }
#pragma unroll
      for (int nt = 0; nt < 2; ++nt)
        bb[nt] = ldfrag(pwb + ((c0 + nt * 16 + lc) << 8) + (kg << 5) + (lg << 3));
#pragma unroll
      for (int mt = 0; mt < 4; ++mt)
#pragma unroll
        for (int nt = 0; nt < 2; ++nt)
          acc[mt][nt] = MFMA16(a[mt], bb[nt], acc[mt][nt]);
    }
    float bias0 = pb[c0 + lc], bias1 = pb[c0 + 16 + lc];
    float* op = outg + (size_t)b * 16384;
#pragma unroll
    for (int mt = 0; mt < 4; ++mt) {
#pragma unroll
      for (int reg = 0; reg < 4; ++reg) {
        int row = mt * 16 + (lg << 2) + reg;
        op[(row << 8) + c0 + lc]      = acc[mt][0][reg] + bias0;
        op[(row << 8) + c0 + 16 + lc] = acc[mt][1][reg] + bias1;
      }
    }
  }
}

// ---------------------------------------------------------------------------
extern "C" void kernel_launch(void* const* d_in, const int* in_sizes, int n_in,
                              void* d_out, int out_size, void* d_ws, size_t ws_size,
                              hipStream_t stream) {
  const float* x    = (const float*)d_in[0];
  const float* c    = (const float*)d_in[1];
  const float* mask = (const float*)d_in[2];
  const float* q_w  = (const float*)d_in[3];
  const float* q_b  = (const float*)d_in[4];
  const float* kv_w = (const float*)d_in[5];
  const float* kv_b = (const float*)d_in[6];
  const float* lsc  = (const float*)d_in[7];
  const float* rpb  = (const float*)d_in[8];
  const float* p_w  = (const float*)d_in[9];
  const float* p_b  = (const float*)d_in[10];

  char* ws = (char*)d_ws;
  ushort* qwb   = (ushort*)(ws);                       // 131072 B
  ushort* kvwb  = (ushort*)(ws + 131072);              // 262144 B
  ushort* pwb   = (ushort*)(ws + 131072 + 262144);     // 131072 B
  float*  bias2 = (float*)(ws + 524288);               // 131072 B
  float*  scale = (float*)(ws + 524288 + 131072);      // 32 B

  prep_kernel<<<64, 256, 0, stream>>>(q_w, kv_w, p_w, rpb, lsc, qwb, kvwb, pwb, bias2, scale);
  wattn_fused<<<4096, 512, 0, stream>>>(x, c, mask, q_b, kv_b, p_b, qwb, kvwb, pwb,
                                        bias2, scale, (float*)d_out);
}

// Round 6
// 555.878 us; speedup vs baseline: 1.1397x; 1.0614x over previous
//
#include <hip/hip_runtime.h>
#include <hip/hip_bf16.h>

// ---------------------------------------------------------------------------
// Fully-fused SwinV2 window attention, one workgroup per window.
//   B=4096 windows, N=64 tokens, DIM=256, H=8 heads, HD=32, NW=1024 masks.
// Round 6 = Round 5 structure (zero LDS transit, swapped Q/K GEMMs, in-reg V
// transpose, 3 barriers, 64KB LDS) with two fixes:
//  - staging loads chunked (4 float4 at a time) -> peak regs fit the 128-reg
//    budget of launch_bounds(512,4) (pool = 512 regs/SIMD / 4 waves)
//  - 4-bit LDS swizzle (row&15)<<5 over all 32 16B-slots -> 2-way (free) bank
//    aliasing on every ds_read_b128/ds_write (was 8-way with (row&7)<<4)
// ---------------------------------------------------------------------------

typedef __attribute__((ext_vector_type(4))) float f32x4;
typedef __attribute__((ext_vector_type(8))) short bf16x8;   // 8 bf16 in 4 VGPRs
typedef __attribute__((ext_vector_type(4))) unsigned int u32x4;
typedef __attribute__((ext_vector_type(2))) unsigned int u32x2;
typedef __attribute__((ext_vector_type(4))) unsigned short u16x4;

#define MFMA16(a, b, c) __builtin_amdgcn_mfma_f32_16x16x32_bf16((a), (b), (c), 0, 0, 0)

union FragAB {
  bf16x8 v;
  ushort u[8];
  u32x4  q4;
  u32x2  q2[2];
};

__device__ __forceinline__ ushort f2b(float f) {
  union { __hip_bfloat16 h; ushort u; } cv;
  cv.h = __float2bfloat16(f);          // native gfx950 cvt, RNE
  return cv.u;
}

__device__ __forceinline__ bf16x8 ldfrag(const ushort* p) {   // 16B-aligned
  FragAB f;
  f.q4 = *(const u32x4*)p;
  return f.v;
}

__device__ __forceinline__ f32x4 fzero() {
  f32x4 z = {0.0f, 0.0f, 0.0f, 0.0f};
  return z;
}

// ---------------------------------------------------------------------------
// Prep: bf16-convert + MFMA-fragment-repack weights; bias2[h][n][m]; scales.
// Packed weight index: o*256 + kg*32 + lg*8 + e  <->  k = 4lg+e | 16+4lg+(e-4)
// ---------------------------------------------------------------------------
__global__ void prep_kernel(const float* __restrict__ qw, const float* __restrict__ kvw,
                            const float* __restrict__ pw, const float* __restrict__ rpb,
                            const float* __restrict__ lsc,
                            ushort* __restrict__ qwb, ushort* __restrict__ kvwb,
                            ushort* __restrict__ pwb, float* __restrict__ bias2,
                            float* __restrict__ scale) {
  int t = blockIdx.x * blockDim.x + threadIdx.x;
  int stride = gridDim.x * blockDim.x;
  for (int i = t; i < 256 * 256; i += stride) {
    int o = i >> 8, rem = i & 255;
    int kg = rem >> 5, r2 = rem & 31, lg = r2 >> 3, e = r2 & 7;
    int k = (kg << 5) + (lg << 2) + (e < 4 ? e : e + 12);
    qwb[i] = f2b(qw[(o << 8) + k]);
    pwb[i] = f2b(pw[(o << 8) + k]);
  }
  for (int i = t; i < 512 * 256; i += stride) {
    int o = i >> 8, rem = i & 255;
    int kg = rem >> 5, r2 = rem & 31, lg = r2 >> 3, e = r2 & 7;
    int k = (kg << 5) + (lg << 2) + (e < 4 ? e : e + 12);
    kvwb[i] = f2b(kvw[(o << 8) + k]);
  }
  // bias2[h][n][m] = rpb_table[RPI[n][m]][h]   (n = query, m = key; m fastest)
  for (int i = t; i < 8 * 64 * 64; i += stride) {
    int h = i >> 12, n = (i >> 6) & 63, m = i & 63;
    int idx = ((n >> 3) - (m >> 3) + 7) * 15 + ((n & 7) - (m & 7) + 7);
    bias2[i] = rpb[idx * 8 + h];
  }
  if (t < 8) scale[t] = __expf(fminf(lsc[t], 4.6051701859880914f));  // log(100)
}

// ---------------------------------------------------------------------------
// Main fused kernel: 512 threads = 8 waves; wave w owns head w / col block w.
// LDS layout: byte = row*512 + (pcb ^ ((row&15)<<5)); all reads use row%16=lc
// so the read swizzle is lc<<5.
// ---------------------------------------------------------------------------
__global__ __launch_bounds__(512, 4)
void wattn_fused(const float* __restrict__ xg, const float* __restrict__ cg,
                 const float* __restrict__ maskg,
                 const float* __restrict__ qb, const float* __restrict__ kvb,
                 const float* __restrict__ pb,
                 const ushort* __restrict__ qwb, const ushort* __restrict__ kvwb,
                 const ushort* __restrict__ pwb,
                 const float* __restrict__ bias2, const float* __restrict__ scaleg,
                 float* __restrict__ outg) {
  __shared__ __align__(16) ushort xs[64 * 256];   // x -> att (swizzled)
  __shared__ __align__(16) ushort cs[64 * 256];   // c (swizzled)

  const int b    = blockIdx.x;
  const int wid  = b & 1023;          // window id (b = batch*1024 + w)
  const int tid  = threadIdx.x;
  const int w    = tid >> 6;          // wave / head 0..7
  const int lane = tid & 63;
  const int lg   = lane >> 4;         // 0..3
  const int lc   = lane & 15;         // 0..15
  const int c0   = w << 5;            // this wave's 32-col block base
  const int sw5  = lc << 5;           // read swizzle ((row&15)<<5, row%16==lc)

  char* xsb = (char*)xs;
  char* csb = (char*)cs;

  // ---- Phase A: stage x -> xs, c -> cs (bf16, packed+swizzled, chunked) ----
  {
    const float4* srcx = (const float4*)(xg + (size_t)b * 16384);
    const float4* srcc = (const float4*)(cg + (size_t)b * 16384);
#pragma unroll
    for (int half = 0; half < 2; ++half) {
      float4 rx[4], rc[4];
#pragma unroll
      for (int j = 0; j < 4; ++j) rx[j] = srcx[tid + (half * 4 + j) * 512];
#pragma unroll
      for (int j = 0; j < 4; ++j) rc[j] = srcc[tid + (half * 4 + j) * 512];
#pragma unroll
      for (int j = 0; j < 4; ++j) {
        int i = tid + (half * 4 + j) * 512;
        int row = i >> 6;
        int colf = (i & 63) << 2;
        int pcb = 2 * ((colf & ~31) + (((colf & 15) >> 2) << 3) + ((colf & 16) ? 4 : 0));
        int off = row * 512 + (pcb ^ ((row & 15) << 5));
        u16x4 p0, p1;
        p0[0] = f2b(rx[j].x); p0[1] = f2b(rx[j].y); p0[2] = f2b(rx[j].z); p0[3] = f2b(rx[j].w);
        p1[0] = f2b(rc[j].x); p1[1] = f2b(rc[j].y); p1[2] = f2b(rc[j].z); p1[3] = f2b(rc[j].w);
        *(u16x4*)(xsb + off) = p0;
        *(u16x4*)(csb + off) = p1;
      }
    }
  }
  __syncthreads();   // ---- bar1 ----

  // ---- Q^T GEMM: D[chan][token] = mfma(Wq, X) -> norm -> qf (same-lane) ----
  bf16x8 qf[4], kf[4];
  {
    f32x4 acc[2][4];   // acc[chan-tile mo][token-tile nt]
#pragma unroll
    for (int mo = 0; mo < 2; ++mo)
#pragma unroll
      for (int nt = 0; nt < 4; ++nt) acc[mo][nt] = fzero();
#pragma unroll
    for (int kg = 0; kg < 8; ++kg) {
      bf16x8 a[4], bb[2];
#pragma unroll
      for (int nt = 0; nt < 4; ++nt) {
        int row = nt * 16 + lc;
        a[nt] = ldfrag((const ushort*)(xsb + row * 512 + (((kg << 6) + (lg << 4)) ^ sw5)));
      }
#pragma unroll
      for (int mo = 0; mo < 2; ++mo)
        bb[mo] = ldfrag(qwb + ((c0 + mo * 16 + lc) << 8) + (kg << 5) + (lg << 3));
#pragma unroll
      for (int mo = 0; mo < 2; ++mo)
#pragma unroll
        for (int nt = 0; nt < 4; ++nt)
          acc[mo][nt] = MFMA16(bb[mo], a[nt], acc[mo][nt]);   // SWAPPED -> transposed
    }
    // bias: chan = c0 + 16*mo + 4*lg + reg  (uniform across lc)
    float bq[2][4];
#pragma unroll
    for (int mo = 0; mo < 2; ++mo)
#pragma unroll
      for (int reg = 0; reg < 4; ++reg) bq[mo][reg] = qb[c0 + mo * 16 + (lg << 2) + reg];
#pragma unroll
    for (int nt = 0; nt < 4; ++nt) {
      float ss = 0.0f;
#pragma unroll
      for (int mo = 0; mo < 2; ++mo)
#pragma unroll
        for (int reg = 0; reg < 4; ++reg) {
          float v = acc[mo][nt][reg] + bq[mo][reg];
          acc[mo][nt][reg] = v;
          ss += v * v;
        }
      ss += __shfl_xor(ss, 16);
      ss += __shfl_xor(ss, 32);
      float inv = 1.0f / fmaxf(sqrtf(ss), 1e-12f);
      FragAB f;
#pragma unroll
      for (int j = 0; j < 4; ++j) {
        f.u[j]     = f2b(acc[0][nt][j] * inv);
        f.u[4 + j] = f2b(acc[1][nt][j] * inv);
      }
      qf[nt] = f.v;
    }
  }

  // ---- K^T GEMM (from cs) -> norm -> kf (same-lane) ----
  {
    f32x4 acc[2][4];
#pragma unroll
    for (int mo = 0; mo < 2; ++mo)
#pragma unroll
      for (int nt = 0; nt < 4; ++nt) acc[mo][nt] = fzero();
#pragma unroll
    for (int kg = 0; kg < 8; ++kg) {
      bf16x8 a[4], bb[2];
#pragma unroll
      for (int nt = 0; nt < 4; ++nt) {
        int row = nt * 16 + lc;
        a[nt] = ldfrag((const ushort*)(csb + row * 512 + (((kg << 6) + (lg << 4)) ^ sw5)));
      }
#pragma unroll
      for (int mo = 0; mo < 2; ++mo)
        bb[mo] = ldfrag(kvwb + ((c0 + mo * 16 + lc) << 8) + (kg << 5) + (lg << 3));
#pragma unroll
      for (int mo = 0; mo < 2; ++mo)
#pragma unroll
        for (int nt = 0; nt < 4; ++nt)
          acc[mo][nt] = MFMA16(bb[mo], a[nt], acc[mo][nt]);   // SWAPPED -> transposed
    }
    float bk[2][4];
#pragma unroll
    for (int mo = 0; mo < 2; ++mo)
#pragma unroll
      for (int reg = 0; reg < 4; ++reg) bk[mo][reg] = kvb[c0 + mo * 16 + (lg << 2) + reg];
#pragma unroll
    for (int nt = 0; nt < 4; ++nt) {
      float ss = 0.0f;
#pragma unroll
      for (int mo = 0; mo < 2; ++mo)
#pragma unroll
        for (int reg = 0; reg < 4; ++reg) {
          float v = acc[mo][nt][reg] + bk[mo][reg];
          acc[mo][nt][reg] = v;
          ss += v * v;
        }
      ss += __shfl_xor(ss, 16);
      ss += __shfl_xor(ss, 32);
      float inv = 1.0f / fmaxf(sqrtf(ss), 1e-12f);
      FragAB f;
#pragma unroll
      for (int j = 0; j < 4; ++j) {
        f.u[j]     = f2b(acc[0][nt][j] * inv);
        f.u[4 + j] = f2b(acc[1][nt][j] * inv);
      }
      kf[nt] = f.v;
    }
  }

  // ---- V GEMM (non-transposed) -> PV A-frags in regs (same-lane) ----
  FragAB av[2][2];   // av[dmt][kt]
  {
    f32x4 acc[4][2];   // acc[token-tile mt][chan-tile dmt]
#pragma unroll
    for (int mt = 0; mt < 4; ++mt)
#pragma unroll
      for (int nt = 0; nt < 2; ++nt) acc[mt][nt] = fzero();
#pragma unroll
    for (int kg = 0; kg < 8; ++kg) {
      bf16x8 a[4], bb[2];
#pragma unroll
      for (int mt = 0; mt < 4; ++mt) {
        int row = mt * 16 + lc;
        a[mt] = ldfrag((const ushort*)(csb + row * 512 + (((kg << 6) + (lg << 4)) ^ sw5)));
      }
#pragma unroll
      for (int nt = 0; nt < 2; ++nt)
        bb[nt] = ldfrag(kvwb + ((256 + c0 + nt * 16 + lc) << 8) + (kg << 5) + (lg << 3));
#pragma unroll
      for (int mt = 0; mt < 4; ++mt)
#pragma unroll
        for (int nt = 0; nt < 2; ++nt)
          acc[mt][nt] = MFMA16(a[mt], bb[nt], acc[mt][nt]);
    }
    float bias0 = kvb[256 + c0 + lc], bias1 = kvb[256 + c0 + 16 + lc];
#pragma unroll
    for (int kt = 0; kt < 2; ++kt)
#pragma unroll
      for (int j = 0; j < 4; ++j) {
        av[0][kt].u[j]     = f2b(acc[2 * kt][0][j] + bias0);
        av[0][kt].u[4 + j] = f2b(acc[2 * kt + 1][0][j] + bias0);
        av[1][kt].u[j]     = f2b(acc[2 * kt][1][j] + bias1);
        av[1][kt].u[4 + j] = f2b(acc[2 * kt + 1][1][j] + bias1);
      }
  }
  __syncthreads();   // ---- bar2: all xs(x)/cs reads done ----

  // ---- Attention: per-nt QK^T -> softmax (mask/bias from L2) -> PV ----
  f32x4 ot[2][4];
#pragma unroll
  for (int dmt = 0; dmt < 2; ++dmt)
#pragma unroll
    for (int nt = 0; nt < 4; ++nt) ot[dmt][nt] = fzero();
  {
    const float sc = scaleg[w];
    const float* b2 = bias2 + (w << 12);
    const float* mq = maskg + (size_t)wid * 4096;
#pragma unroll
    for (int nt = 0; nt < 4; ++nt) {
      f32x4 st[4];
#pragma unroll
      for (int mt = 0; mt < 4; ++mt)
        st[mt] = MFMA16(kf[mt], qf[nt], fzero());
      const int n = nt * 16 + lc;
      float mx = -3.0e38f;
#pragma unroll
      for (int mt = 0; mt < 4; ++mt) {
        f32x4 bv = *(const f32x4*)(b2 + (n << 6) + (mt << 4) + (lg << 2));
        f32x4 mk = *(const f32x4*)(mq + (n << 6) + (mt << 4) + (lg << 2));
#pragma unroll
        for (int reg = 0; reg < 4; ++reg) {
          float val = st[mt][reg] * sc + bv[reg] + mk[reg];
          st[mt][reg] = val;
          mx = fmaxf(mx, val);
        }
      }
      mx = fmaxf(mx, __shfl_xor(mx, 16));
      mx = fmaxf(mx, __shfl_xor(mx, 32));
      float sm = 0.0f;
#pragma unroll
      for (int mt = 0; mt < 4; ++mt)
#pragma unroll
        for (int reg = 0; reg < 4; ++reg) {
          float e = __expf(st[mt][reg] - mx);
          st[mt][reg] = e;
          sm += e;
        }
      sm += __shfl_xor(sm, 16);
      sm += __shfl_xor(sm, 32);
      float inv = 1.0f / sm;
#pragma unroll
      for (int kt = 0; kt < 2; ++kt) {
        FragAB pfr;
#pragma unroll
        for (int j = 0; j < 4; ++j) {
          pfr.u[j]     = f2b(st[2 * kt][j] * inv);
          pfr.u[4 + j] = f2b(st[2 * kt + 1][j] * inv);
        }
#pragma unroll
        for (int dmt = 0; dmt < 2; ++dmt)
          ot[dmt][nt] = MFMA16(av[dmt][kt].v, pfr.v, ot[dmt][nt]);
      }
    }
  }

  // ---- att-write into xs: one b128 per nt ----
#pragma unroll
  for (int nt = 0; nt < 4; ++nt) {
    int row = nt * 16 + lc;
    FragAB o8;
#pragma unroll
    for (int j = 0; j < 4; ++j) {
      o8.u[j]     = f2b(ot[0][nt][j]);
      o8.u[4 + j] = f2b(ot[1][nt][j]);
    }
    *(u32x4*)(xsb + row * 512 + (((w << 6) + (lg << 4)) ^ sw5)) = o8.q4;
  }
  __syncthreads();   // ---- bar3: att complete ----

  // ---- Proj GEMM: out = att @ pw^T + pb  (f32 store) ----
  {
    f32x4 acc[4][2];
#pragma unroll
    for (int mt = 0; mt < 4; ++mt)
#pragma unroll
      for (int nt = 0; nt < 2; ++nt) acc[mt][nt] = fzero();
#pragma unroll
    for (int kg = 0; kg < 8; ++kg) {
      bf16x8 a[4], bb[2];
#pragma unroll
      for (int mt = 0; mt < 4; ++mt) {
        int row = mt * 16 + lc;
        a[mt] = ldfrag((const ushort*)(xsb + row * 512 + (((kg << 6) + (lg << 4)) ^ sw5)));
      }
#pragma unroll
      for (int nt = 0; nt < 2; ++nt)
        bb[nt] = ldfrag(pwb + ((c0 + nt * 16 + lc) << 8) + (kg << 5) + (lg << 3));
#pragma unroll
      for (int mt = 0; mt < 4; ++mt)
#pragma unroll
        for (int nt = 0; nt < 2; ++nt)
          acc[mt][nt] = MFMA16(a[mt], bb[nt], acc[mt][nt]);
    }
    float bias0 = pb[c0 + lc], bias1 = pb[c0 + 16 + lc];
    float* op = outg + (size_t)b * 16384;
#pragma unroll
    for (int mt = 0; mt < 4; ++mt) {
#pragma unroll
      for (int reg = 0; reg < 4; ++reg) {
        int row = mt * 16 + (lg << 2) + reg;
        op[(row << 8) + c0 + lc]      = acc[mt][0][reg] + bias0;
        op[(row << 8) + c0 + 16 + lc] = acc[mt][1][reg] + bias1;
      }
    }
  }
}

// ---------------------------------------------------------------------------
extern "C" void kernel_launch(void* const* d_in, const int* in_sizes, int n_in,
                              void* d_out, int out_size, void* d_ws, size_t ws_size,
                              hipStream_t stream) {
  const float* x    = (const float*)d_in[0];
  const float* c    = (const float*)d_in[1];
  const float* mask = (const float*)d_in[2];
  const float* q_w  = (const float*)d_in[3];
  const float* q_b  = (const float*)d_in[4];
  const float* kv_w = (const float*)d_in[5];
  const float* kv_b = (const float*)d_in[6];
  const float* lsc  = (const float*)d_in[7];
  const float* rpb  = (const float*)d_in[8];
  const float* p_w  = (const float*)d_in[9];
  const float* p_b  = (const float*)d_in[10];

  char* ws = (char*)d_ws;
  ushort* qwb   = (ushort*)(ws);                       // 131072 B
  ushort* kvwb  = (ushort*)(ws + 131072);              // 262144 B
  ushort* pwb   = (ushort*)(ws + 131072 + 262144);     // 131072 B
  float*  bias2 = (float*)(ws + 524288);               // 131072 B
  float*  scale = (float*)(ws + 524288 + 131072);      // 32 B

  prep_kernel<<<64, 256, 0, stream>>>(q_w, kv_w, p_w, rpb, lsc, qwb, kvwb, pwb, bias2, scale);
  wattn_fused<<<4096, 512, 0, stream>>>(x, c, mask, q_b, kv_b, p_b, qwb, kvwb, pwb,
                                        bias2, scale, (float*)d_out);
}

// Round 7
// 506.650 us; speedup vs baseline: 1.2504x; 1.0972x over previous
//
#include <hip/hip_runtime.h>
#include <hip/hip_bf16.h>

// ---------------------------------------------------------------------------
// Fully-fused SwinV2 window attention, one workgroup per window.
//   B=4096 windows, N=64 tokens, DIM=256, H=8 heads, HD=32, NW=1024 masks.
// Round 7 = Round 6 structure (zero LDS transit, swapped Q/K GEMMs, in-reg V
// transpose, 3 barriers, 64KB LDS, 2-way-free swizzle) with the register
// budget FIXED at launch_bounds(512,2): 256 regs/wave, 1 block/CU, ZERO spill
// (R4-R6 proved the algorithm needs ~140 regs and cannot fit the 128-reg
// budget of 4 waves/EU -> 500MB of scratch traffic dominated).
// ---------------------------------------------------------------------------

typedef __attribute__((ext_vector_type(4))) float f32x4;
typedef __attribute__((ext_vector_type(8))) short bf16x8;   // 8 bf16 in 4 VGPRs
typedef __attribute__((ext_vector_type(4))) unsigned int u32x4;
typedef __attribute__((ext_vector_type(2))) unsigned int u32x2;
typedef __attribute__((ext_vector_type(4))) unsigned short u16x4;

#define MFMA16(a, b, c) __builtin_amdgcn_mfma_f32_16x16x32_bf16((a), (b), (c), 0, 0, 0)

union FragAB {
  bf16x8 v;
  ushort u[8];
  u32x4  q4;
  u32x2  q2[2];
};

__device__ __forceinline__ ushort f2b(float f) {
  union { __hip_bfloat16 h; ushort u; } cv;
  cv.h = __float2bfloat16(f);          // native gfx950 cvt, RNE
  return cv.u;
}

__device__ __forceinline__ bf16x8 ldfrag(const ushort* p) {   // 16B-aligned
  FragAB f;
  f.q4 = *(const u32x4*)p;
  return f.v;
}

__device__ __forceinline__ f32x4 fzero() {
  f32x4 z = {0.0f, 0.0f, 0.0f, 0.0f};
  return z;
}

// ---------------------------------------------------------------------------
// Prep: bf16-convert + MFMA-fragment-repack weights; bias2[h][n][m]; scales.
// Packed weight index: o*256 + kg*32 + lg*8 + e  <->  k = 4lg+e | 16+4lg+(e-4)
// ---------------------------------------------------------------------------
__global__ void prep_kernel(const float* __restrict__ qw, const float* __restrict__ kvw,
                            const float* __restrict__ pw, const float* __restrict__ rpb,
                            const float* __restrict__ lsc,
                            ushort* __restrict__ qwb, ushort* __restrict__ kvwb,
                            ushort* __restrict__ pwb, float* __restrict__ bias2,
                            float* __restrict__ scale) {
  int t = blockIdx.x * blockDim.x + threadIdx.x;
  int stride = gridDim.x * blockDim.x;
  for (int i = t; i < 256 * 256; i += stride) {
    int o = i >> 8, rem = i & 255;
    int kg = rem >> 5, r2 = rem & 31, lg = r2 >> 3, e = r2 & 7;
    int k = (kg << 5) + (lg << 2) + (e < 4 ? e : e + 12);
    qwb[i] = f2b(qw[(o << 8) + k]);
    pwb[i] = f2b(pw[(o << 8) + k]);
  }
  for (int i = t; i < 512 * 256; i += stride) {
    int o = i >> 8, rem = i & 255;
    int kg = rem >> 5, r2 = rem & 31, lg = r2 >> 3, e = r2 & 7;
    int k = (kg << 5) + (lg << 2) + (e < 4 ? e : e + 12);
    kvwb[i] = f2b(kvw[(o << 8) + k]);
  }
  // bias2[h][n][m] = rpb_table[RPI[n][m]][h]   (n = query, m = key; m fastest)
  for (int i = t; i < 8 * 64 * 64; i += stride) {
    int h = i >> 12, n = (i >> 6) & 63, m = i & 63;
    int idx = ((n >> 3) - (m >> 3) + 7) * 15 + ((n & 7) - (m & 7) + 7);
    bias2[i] = rpb[idx * 8 + h];
  }
  if (t < 8) scale[t] = __expf(fminf(lsc[t], 4.6051701859880914f));  // log(100)
}

// ---------------------------------------------------------------------------
// Main fused kernel: 512 threads = 8 waves; wave w owns head w / col block w.
// LDS layout: byte = row*512 + (pcb ^ ((row&15)<<5)); all reads use row%16=lc
// so the read swizzle is lc<<5 -> 2-way (free) bank aliasing everywhere.
// ---------------------------------------------------------------------------
__global__ __launch_bounds__(512, 2)
void wattn_fused(const float* __restrict__ xg, const float* __restrict__ cg,
                 const float* __restrict__ maskg,
                 const float* __restrict__ qb, const float* __restrict__ kvb,
                 const float* __restrict__ pb,
                 const ushort* __restrict__ qwb, const ushort* __restrict__ kvwb,
                 const ushort* __restrict__ pwb,
                 const float* __restrict__ bias2, const float* __restrict__ scaleg,
                 float* __restrict__ outg) {
  __shared__ __align__(16) ushort xs[64 * 256];   // x -> att (swizzled)
  __shared__ __align__(16) ushort cs[64 * 256];   // c (swizzled)

  const int b    = blockIdx.x;
  const int wid  = b & 1023;          // window id (b = batch*1024 + w)
  const int tid  = threadIdx.x;
  const int w    = tid >> 6;          // wave / head 0..7
  const int lane = tid & 63;
  const int lg   = lane >> 4;         // 0..3
  const int lc   = lane & 15;         // 0..15
  const int c0   = w << 5;            // this wave's 32-col block base
  const int sw5  = lc << 5;           // read swizzle ((row&15)<<5, row%16==lc)

  char* xsb = (char*)xs;
  char* csb = (char*)cs;

  // ---- Phase A: stage x -> xs, c -> cs (bf16, packed+swizzled) ----
  {
    const float4* srcx = (const float4*)(xg + (size_t)b * 16384);
    const float4* srcc = (const float4*)(cg + (size_t)b * 16384);
    float4 rx[8], rc[8];
#pragma unroll
    for (int it = 0; it < 8; ++it) rx[it] = srcx[tid + it * 512];
#pragma unroll
    for (int it = 0; it < 8; ++it) rc[it] = srcc[tid + it * 512];
#pragma unroll
    for (int it = 0; it < 8; ++it) {
      int i = tid + it * 512;
      int row = i >> 6;
      int colf = (i & 63) << 2;
      int pcb = 2 * ((colf & ~31) + (((colf & 15) >> 2) << 3) + ((colf & 16) ? 4 : 0));
      int off = row * 512 + (pcb ^ ((row & 15) << 5));
      u16x4 p0, p1;
      p0[0] = f2b(rx[it].x); p0[1] = f2b(rx[it].y); p0[2] = f2b(rx[it].z); p0[3] = f2b(rx[it].w);
      p1[0] = f2b(rc[it].x); p1[1] = f2b(rc[it].y); p1[2] = f2b(rc[it].z); p1[3] = f2b(rc[it].w);
      *(u16x4*)(xsb + off) = p0;
      *(u16x4*)(csb + off) = p1;
    }
  }
  __syncthreads();   // ---- bar1 ----

  // ---- Q^T GEMM: D[chan][token] = mfma(Wq, X) -> norm -> qf (same-lane) ----
  bf16x8 qf[4], kf[4];
  {
    f32x4 acc[2][4];   // acc[chan-tile mo][token-tile nt]
#pragma unroll
    for (int mo = 0; mo < 2; ++mo)
#pragma unroll
      for (int nt = 0; nt < 4; ++nt) acc[mo][nt] = fzero();
#pragma unroll
    for (int kg = 0; kg < 8; ++kg) {
      bf16x8 a[4], bb[2];
#pragma unroll
      for (int nt = 0; nt < 4; ++nt) {
        int row = nt * 16 + lc;
        a[nt] = ldfrag((const ushort*)(xsb + row * 512 + (((kg << 6) + (lg << 4)) ^ sw5)));
      }
#pragma unroll
      for (int mo = 0; mo < 2; ++mo)
        bb[mo] = ldfrag(qwb + ((c0 + mo * 16 + lc) << 8) + (kg << 5) + (lg << 3));
#pragma unroll
      for (int mo = 0; mo < 2; ++mo)
#pragma unroll
        for (int nt = 0; nt < 4; ++nt)
          acc[mo][nt] = MFMA16(bb[mo], a[nt], acc[mo][nt]);   // SWAPPED -> transposed
    }
    // bias: chan = c0 + 16*mo + 4*lg + reg  (uniform across lc)
    float bq[2][4];
#pragma unroll
    for (int mo = 0; mo < 2; ++mo)
#pragma unroll
      for (int reg = 0; reg < 4; ++reg) bq[mo][reg] = qb[c0 + mo * 16 + (lg << 2) + reg];
#pragma unroll
    for (int nt = 0; nt < 4; ++nt) {
      float ss = 0.0f;
#pragma unroll
      for (int mo = 0; mo < 2; ++mo)
#pragma unroll
        for (int reg = 0; reg < 4; ++reg) {
          float v = acc[mo][nt][reg] + bq[mo][reg];
          acc[mo][nt][reg] = v;
          ss += v * v;
        }
      ss += __shfl_xor(ss, 16);
      ss += __shfl_xor(ss, 32);
      float inv = 1.0f / fmaxf(sqrtf(ss), 1e-12f);
      FragAB f;
#pragma unroll
      for (int j = 0; j < 4; ++j) {
        f.u[j]     = f2b(acc[0][nt][j] * inv);
        f.u[4 + j] = f2b(acc[1][nt][j] * inv);
      }
      qf[nt] = f.v;
    }
  }

  // ---- K^T GEMM (from cs) -> norm -> kf (same-lane) ----
  {
    f32x4 acc[2][4];
#pragma unroll
    for (int mo = 0; mo < 2; ++mo)
#pragma unroll
      for (int nt = 0; nt < 4; ++nt) acc[mo][nt] = fzero();
#pragma unroll
    for (int kg = 0; kg < 8; ++kg) {
      bf16x8 a[4], bb[2];
#pragma unroll
      for (int nt = 0; nt < 4; ++nt) {
        int row = nt * 16 + lc;
        a[nt] = ldfrag((const ushort*)(csb + row * 512 + (((kg << 6) + (lg << 4)) ^ sw5)));
      }
#pragma unroll
      for (int mo = 0; mo < 2; ++mo)
        bb[mo] = ldfrag(kvwb + ((c0 + mo * 16 + lc) << 8) + (kg << 5) + (lg << 3));
#pragma unroll
      for (int mo = 0; mo < 2; ++mo)
#pragma unroll
        for (int nt = 0; nt < 4; ++nt)
          acc[mo][nt] = MFMA16(bb[mo], a[nt], acc[mo][nt]);   // SWAPPED -> transposed
    }
    float bk[2][4];
#pragma unroll
    for (int mo = 0; mo < 2; ++mo)
#pragma unroll
      for (int reg = 0; reg < 4; ++reg) bk[mo][reg] = kvb[c0 + mo * 16 + (lg << 2) + reg];
#pragma unroll
    for (int nt = 0; nt < 4; ++nt) {
      float ss = 0.0f;
#pragma unroll
      for (int mo = 0; mo < 2; ++mo)
#pragma unroll
        for (int reg = 0; reg < 4; ++reg) {
          float v = acc[mo][nt][reg] + bk[mo][reg];
          acc[mo][nt][reg] = v;
          ss += v * v;
        }
      ss += __shfl_xor(ss, 16);
      ss += __shfl_xor(ss, 32);
      float inv = 1.0f / fmaxf(sqrtf(ss), 1e-12f);
      FragAB f;
#pragma unroll
      for (int j = 0; j < 4; ++j) {
        f.u[j]     = f2b(acc[0][nt][j] * inv);
        f.u[4 + j] = f2b(acc[1][nt][j] * inv);
      }
      kf[nt] = f.v;
    }
  }

  // ---- V GEMM (non-transposed) -> PV A-frags in regs (same-lane) ----
  FragAB av[2][2];   // av[dmt][kt]
  {
    f32x4 acc[4][2];   // acc[token-tile mt][chan-tile dmt]
#pragma unroll
    for (int mt = 0; mt < 4; ++mt)
#pragma unroll
      for (int nt = 0; nt < 2; ++nt) acc[mt][nt] = fzero();
#pragma unroll
    for (int kg = 0; kg < 8; ++kg) {
      bf16x8 a[4], bb[2];
#pragma unroll
      for (int mt = 0; mt < 4; ++mt) {
        int row = mt * 16 + lc;
        a[mt] = ldfrag((const ushort*)(csb + row * 512 + (((kg << 6) + (lg << 4)) ^ sw5)));
      }
#pragma unroll
      for (int nt = 0; nt < 2; ++nt)
        bb[nt] = ldfrag(kvwb + ((256 + c0 + nt * 16 + lc) << 8) + (kg << 5) + (lg << 3));
#pragma unroll
      for (int mt = 0; mt < 4; ++mt)
#pragma unroll
        for (int nt = 0; nt < 2; ++nt)
          acc[mt][nt] = MFMA16(a[mt], bb[nt], acc[mt][nt]);
    }
    float bias0 = kvb[256 + c0 + lc], bias1 = kvb[256 + c0 + 16 + lc];
#pragma unroll
    for (int kt = 0; kt < 2; ++kt)
#pragma unroll
      for (int j = 0; j < 4; ++j) {
        av[0][kt].u[j]     = f2b(acc[2 * kt][0][j] + bias0);
        av[0][kt].u[4 + j] = f2b(acc[2 * kt + 1][0][j] + bias0);
        av[1][kt].u[j]     = f2b(acc[2 * kt][1][j] + bias1);
        av[1][kt].u[4 + j] = f2b(acc[2 * kt + 1][1][j] + bias1);
      }
  }
  __syncthreads();   // ---- bar2: all xs(x)/cs reads done ----

  // ---- Attention: per-nt QK^T -> softmax (mask/bias from L2) -> PV ----
  f32x4 ot[2][4];
#pragma unroll
  for (int dmt = 0; dmt < 2; ++dmt)
#pragma unroll
    for (int nt = 0; nt < 4; ++nt) ot[dmt][nt] = fzero();
  {
    const float sc = scaleg[w];
    const float* b2 = bias2 + (w << 12);
    const float* mq = maskg + (size_t)wid * 4096;
#pragma unroll
    for (int nt = 0; nt < 4; ++nt) {
      f32x4 st[4];
#pragma unroll
      for (int mt = 0; mt < 4; ++mt)
        st[mt] = MFMA16(kf[mt], qf[nt], fzero());
      const int n = nt * 16 + lc;
      float mx = -3.0e38f;
#pragma unroll
      for (int mt = 0; mt < 4; ++mt) {
        f32x4 bv = *(const f32x4*)(b2 + (n << 6) + (mt << 4) + (lg << 2));
        f32x4 mk = *(const f32x4*)(mq + (n << 6) + (mt << 4) + (lg << 2));
#pragma unroll
        for (int reg = 0; reg < 4; ++reg) {
          float val = st[mt][reg] * sc + bv[reg] + mk[reg];
          st[mt][reg] = val;
          mx = fmaxf(mx, val);
        }
      }
      mx = fmaxf(mx, __shfl_xor(mx, 16));
      mx = fmaxf(mx, __shfl_xor(mx, 32));
      float sm = 0.0f;
#pragma unroll
      for (int mt = 0; mt < 4; ++mt)
#pragma unroll
        for (int reg = 0; reg < 4; ++reg) {
          float e = __expf(st[mt][reg] - mx);
          st[mt][reg] = e;
          sm += e;
        }
      sm += __shfl_xor(sm, 16);
      sm += __shfl_xor(sm, 32);
      float inv = 1.0f / sm;
#pragma unroll
      for (int kt = 0; kt < 2; ++kt) {
        FragAB pfr;
#pragma unroll
        for (int j = 0; j < 4; ++j) {
          pfr.u[j]     = f2b(st[2 * kt][j] * inv);
          pfr.u[4 + j] = f2b(st[2 * kt + 1][j] * inv);
        }
#pragma unroll
        for (int dmt = 0; dmt < 2; ++dmt)
          ot[dmt][nt] = MFMA16(av[dmt][kt].v, pfr.v, ot[dmt][nt]);
      }
    }
  }

  // ---- att-write into xs: one b128 per nt ----
#pragma unroll
  for (int nt = 0; nt < 4; ++nt) {
    int row = nt * 16 + lc;
    FragAB o8;
#pragma unroll
    for (int j = 0; j < 4; ++j) {
      o8.u[j]     = f2b(ot[0][nt][j]);
      o8.u[4 + j] = f2b(ot[1][nt][j]);
    }
    *(u32x4*)(xsb + row * 512 + (((w << 6) + (lg << 4)) ^ sw5)) = o8.q4;
  }
  __syncthreads();   // ---- bar3: att complete ----

  // ---- Proj GEMM: out = att @ pw^T + pb  (f32 store) ----
  {
    f32x4 acc[4][2];
#pragma unroll
    for (int mt = 0; mt < 4; ++mt)
#pragma unroll
      for (int nt = 0; nt < 2; ++nt) acc[mt][nt] = fzero();
#pragma unroll
    for (int kg = 0; kg < 8; ++kg) {
      bf16x8 a[4], bb[2];
#pragma unroll
      for (int mt = 0; mt < 4; ++mt) {
        int row = mt * 16 + lc;
        a[mt] = ldfrag((const ushort*)(xsb + row * 512 + (((kg << 6) + (lg << 4)) ^ sw5)));
      }
#pragma unroll
      for (int nt = 0; nt < 2; ++nt)
        bb[nt] = ldfrag(pwb + ((c0 + nt * 16 + lc) << 8) + (kg << 5) + (lg << 3));
#pragma unroll
      for (int mt = 0; mt < 4; ++mt)
#pragma unroll
        for (int nt = 0; nt < 2; ++nt)
          acc[mt][nt] = MFMA16(a[mt], bb[nt], acc[mt][nt]);
    }
    float bias0 = pb[c0 + lc], bias1 = pb[c0 + 16 + lc];
    float* op = outg + (size_t)b * 16384;
#pragma unroll
    for (int mt = 0; mt < 4; ++mt) {
#pragma unroll
      for (int reg = 0; reg < 4; ++reg) {
        int row = mt * 16 + (lg << 2) + reg;
        op[(row << 8) + c0 + lc]      = acc[mt][0][reg] + bias0;
        op[(row << 8) + c0 + 16 + lc] = acc[mt][1][reg] + bias1;
      }
    }
  }
}

// ---------------------------------------------------------------------------
extern "C" void kernel_launch(void* const* d_in, const int* in_sizes, int n_in,
                              void* d_out, int out_size, void* d_ws, size_t ws_size,
                              hipStream_t stream) {
  const float* x    = (const float*)d_in[0];
  const float* c    = (const float*)d_in[1];
  const float* mask = (const float*)d_in[2];
  const float* q_w  = (const float*)d_in[3];
  const float* q_b  = (const float*)d_in[4];
  const float* kv_w = (const float*)d_in[5];
  const float* kv_b = (const float*)d_in[6];
  const float* lsc  = (const float*)d_in[7];
  const float* rpb  = (const float*)d_in[8];
  const float* p_w  = (const float*)d_in[9];
  const float* p_b  = (const float*)d_in[10];

  char* ws = (char*)d_ws;
  ushort* qwb   = (ushort*)(ws);                       // 131072 B
  ushort* kvwb  = (ushort*)(ws + 131072);              // 262144 B
  ushort* pwb   = (ushort*)(ws + 131072 + 262144);     // 131072 B
  float*  bias2 = (float*)(ws + 524288);               // 131072 B
  float*  scale = (float*)(ws + 524288 + 131072);      // 32 B

  prep_kernel<<<64, 256, 0, stream>>>(q_w, kv_w, p_w, rpb, lsc, qwb, kvwb, pwb, bias2, scale);
  wattn_fused<<<4096, 512, 0, stream>>>(x, c, mask, q_b, kv_b, p_b, qwb, kvwb, pwb,
                                        bias2, scale, (float*)d_out);
}